// Round 2
// baseline (1461.771 us; speedup 1.0000x reference)
//
#include <hip/hip_runtime.h>
#include <hip/hip_bf16.h>

// ---------------------------------------------------------------------------
// Transformer encoder, B=8 T=1024 D_IN=320 L=6 H=8 DK=DV=64 DM=512 DI=2048.
// bf16 MFMA GEMMs (m97-style 2-phase structure), fused flash attention with
// swapped QK^T, f32 residual stream for accuracy.
// R1: attention rewritten — barrier-free independent waves, KVBLK=64,
//     register K-prefetch double-buffer, defer-max, setprio.
// ---------------------------------------------------------------------------

typedef unsigned short bh16;                                  // bf16 bits
typedef __bf16 bf16x8 __attribute__((ext_vector_type(8)));
typedef float f32x4 __attribute__((ext_vector_type(4)));
typedef unsigned int u32x4 __attribute__((ext_vector_type(4)));
typedef unsigned int u32x2 __attribute__((ext_vector_type(2)));

#define DEVI static __device__ __forceinline__

DEVI bh16 f2bf(float f) {
  union { float f; unsigned u; } x; x.f = f;
  unsigned r = x.u + 0x7fffu + ((x.u >> 16) & 1u);
  return (bh16)(r >> 16);
}
DEVI float bf2f(bh16 u) {
  union { unsigned u; float f; } x; x.u = ((unsigned)u) << 16; return x.f;
}
DEVI bf16x8 ld16(const bh16* p) {
  return __builtin_bit_cast(bf16x8, *(const u32x4*)p);
}
DEVI f32x4 mfma16(bf16x8 a, bf16x8 b, f32x4 c) {
  return __builtin_amdgcn_mfma_f32_16x16x32_bf16(a, b, c, 0, 0, 0);
}
DEVI void async16(const void* g, void* l) {
  __builtin_amdgcn_global_load_lds(
      (const __attribute__((address_space(1))) void*)g,
      (__attribute__((address_space(3))) void*)l, 16, 0, 0);
}

// ---------------------------------------------------------------------------
// Weight transpose + f32->bf16 convert: in [K][N] f32 -> out [N][K] bf16.
// grid: (N/32, K/32, Layers)
// ---------------------------------------------------------------------------
__global__ __launch_bounds__(256) void tcvt(
    const float* __restrict__ in, bh16* __restrict__ out,
    int K, int N, long long inLS, long long outLS, int rowOff) {
  int l = blockIdx.z;
  in += (size_t)l * inLS;
  out += (size_t)l * outLS + (size_t)rowOff * K;
  __shared__ float t[32][33];
  int n0 = blockIdx.x * 32, k0 = blockIdx.y * 32;
  int tx = threadIdx.x & 31, ty = threadIdx.x >> 5;  // 32 x 8
#pragma unroll
  for (int i = 0; i < 4; i++)
    t[ty + 8 * i][tx] = in[(size_t)(k0 + ty + 8 * i) * N + n0 + tx];
  __syncthreads();
#pragma unroll
  for (int i = 0; i < 4; i++)
    out[(size_t)(n0 + ty + 8 * i) * K + k0 + tx] = f2bf(t[tx][ty + 8 * i]);
}

// bias concat: bq|bk|bv -> [L][1536] f32
__global__ __launch_bounds__(256) void bcat(
    const float* __restrict__ bq, const float* __restrict__ bk,
    const float* __restrict__ bv, float* __restrict__ out) {
  int l = blockIdx.x;
  for (int j = threadIdx.x; j < 1536; j += 256) {
    float v = (j < 512) ? bq[l * 512 + j]
            : (j < 1024) ? bk[l * 512 + j - 512] : bv[l * 512 + j - 1024];
    out[l * 1536 + j] = v;
  }
}

// f32 -> bf16 convert (padded_input)
__global__ __launch_bounds__(256) void cvt_in(
    const float* __restrict__ in, bh16* __restrict__ out, int n4) {
  int i = blockIdx.x * 256 + threadIdx.x;
  if (i < n4) {
    float4 v = ((const float4*)in)[i];
    u32x2 pk;
    pk[0] = (unsigned)f2bf(v.x) | ((unsigned)f2bf(v.y) << 16);
    pk[1] = (unsigned)f2bf(v.z) | ((unsigned)f2bf(v.w) << 16);
    *(u32x2*)(out + (size_t)i * 4) = pk;
  }
}

// ---------------------------------------------------------------------------
// GEMM: C[M][N] = A[M][K](bf16) * Bt[N][K](bf16)^T + bias, m97-style.
// 256 threads (4 waves, 2x2), BK=64, global_load_lds staging, 16x16x32 MFMA.
// ---------------------------------------------------------------------------
template <int BM, int BN, int RELU, int OUTF32>
__global__ __launch_bounds__(256, 2) void gemm_bt(
    const bh16* __restrict__ A, const bh16* __restrict__ Bt,
    const float* __restrict__ bias, void* __restrict__ Cout,
    int M, int N, int K) {
  constexpr int BK = 64;
  __shared__ __align__(16) bh16 As[BM * BK];
  __shared__ __align__(16) bh16 Bs[BN * BK];
  const int tid = threadIdx.x;
  const int wave = tid >> 6, lane = tid & 63;
  const int lq = lane & 15, grp = lane >> 4;
  const int m0 = blockIdx.y * BM, n0 = blockIdx.x * BN;
  constexpr int FM = BM / 32, FN = BN / 32;
  const int wr = wave >> 1, wc = wave & 1;
  f32x4 acc[FM][FN] = {};

  const int nk = K / BK;
  for (int kt = 0; kt < nk; ++kt) {
#pragma unroll
    for (int i = 0; i < BM / 32; ++i) {
      int off = i * 4096 + wave * 1024 + lane * 16;
      int row = off >> 7, col = off & 127;
      const char* g = (const char*)A + ((size_t)(m0 + row) * K + kt * BK) * 2 + col;
      async16(g, (char*)As + off);
    }
#pragma unroll
    for (int i = 0; i < BN / 32; ++i) {
      int off = i * 4096 + wave * 1024 + lane * 16;
      int row = off >> 7, col = off & 127;
      const char* g = (const char*)Bt + ((size_t)(n0 + row) * K + kt * BK) * 2 + col;
      async16(g, (char*)Bs + off);
    }
    __syncthreads();
#pragma unroll
    for (int kk = 0; kk < 2; ++kk) {
      bf16x8 af[FM], bfr[FN];
#pragma unroll
      for (int i = 0; i < FM; ++i) {
        int row = wr * (BM / 2) + i * 16 + lq;
        af[i] = ld16(As + row * BK + kk * 32 + grp * 8);
      }
#pragma unroll
      for (int j = 0; j < FN; ++j) {
        int row = wc * (BN / 2) + j * 16 + lq;
        bfr[j] = ld16(Bs + row * BK + kk * 32 + grp * 8);
      }
#pragma unroll
      for (int i = 0; i < FM; ++i)
#pragma unroll
        for (int j = 0; j < FN; ++j)
          acc[i][j] = mfma16(af[i], bfr[j], acc[i][j]);
    }
    __syncthreads();
  }
  // epilogue: D layout col=lane&15, row=(lane>>4)*4+r  [m89-verified]
#pragma unroll
  for (int i = 0; i < FM; ++i) {
#pragma unroll
    for (int j = 0; j < FN; ++j) {
      int col = n0 + wc * (BN / 2) + j * 16 + lq;
      float bv = bias[col];
#pragma unroll
      for (int r = 0; r < 4; ++r) {
        int row = m0 + wr * (BM / 2) + i * 16 + grp * 4 + r;
        float v = acc[i][j][r] + bv;
        if (RELU) v = fmaxf(v, 0.f);
        if (OUTF32) ((float*)Cout)[(size_t)row * N + col] = v;
        else ((bh16*)Cout)[(size_t)row * N + col] = f2bf(v);
      }
    }
  }
}

// ---------------------------------------------------------------------------
// LayerNorm after input projection: xb/xf = LN(in)*g+b + pe[t]
// one wave per row (512 cols, 8/lane)
// ---------------------------------------------------------------------------
__global__ __launch_bounds__(256) void ln_pe_k(
    const float* __restrict__ in, const float* __restrict__ g,
    const float* __restrict__ bta, const float* __restrict__ pe,
    float* __restrict__ xf, bh16* __restrict__ xb) {
  int wave = threadIdx.x >> 6, lane = threadIdx.x & 63;
  int row = blockIdx.x * 4 + wave;
  int t = row & 1023;
  const float* xr = in + (size_t)row * 512 + lane * 8;
  float4 a0 = ((const float4*)xr)[0], a1 = ((const float4*)xr)[1];
  float v[8] = {a0.x, a0.y, a0.z, a0.w, a1.x, a1.y, a1.z, a1.w};
  float s = 0.f, ss = 0.f;
#pragma unroll
  for (int j = 0; j < 8; j++) { s += v[j]; ss += v[j] * v[j]; }
#pragma unroll
  for (int m = 1; m < 64; m <<= 1) { s += __shfl_xor(s, m); ss += __shfl_xor(ss, m); }
  float mu = s * (1.f / 512.f);
  float rstd = rsqrtf(ss * (1.f / 512.f) - mu * mu + 1e-5f);
  int c0 = lane * 8;
  float o[8];
  u32x4 pk;
#pragma unroll
  for (int j = 0; j < 8; j++) {
    int c = c0 + j;
    o[j] = (v[j] - mu) * rstd * g[c] + bta[c] + pe[(size_t)t * 512 + c];
  }
  float4* xo = (float4*)(xf + (size_t)row * 512 + c0);
  xo[0] = make_float4(o[0], o[1], o[2], o[3]);
  xo[1] = make_float4(o[4], o[5], o[6], o[7]);
#pragma unroll
  for (int j = 0; j < 4; j++)
    pk[j] = (unsigned)f2bf(o[2 * j]) | ((unsigned)f2bf(o[2 * j + 1]) << 16);
  *(u32x4*)(xb + (size_t)row * 512 + c0) = pk;
}

// ---------------------------------------------------------------------------
// LayerNorm with residual + pad-mask: out = LN(gout + res)*g+b * nonpad
// ---------------------------------------------------------------------------
__global__ __launch_bounds__(256) void ln_res_k(
    const float* __restrict__ gout, const float* __restrict__ res,
    const float* __restrict__ g, const float* __restrict__ bta,
    const int* __restrict__ lens,
    float* __restrict__ xf, bh16* __restrict__ xb) {
  int wave = threadIdx.x >> 6, lane = threadIdx.x & 63;
  int row = blockIdx.x * 4 + wave;
  int b = row >> 10, t = row & 1023;
  float nonpad = (t < lens[b]) ? 1.f : 0.f;
  const float* xr = gout + (size_t)row * 512 + lane * 8;
  const float* rr = res + (size_t)row * 512 + lane * 8;
  float4 a0 = ((const float4*)xr)[0], a1 = ((const float4*)xr)[1];
  float4 r0 = ((const float4*)rr)[0], r1 = ((const float4*)rr)[1];
  float v[8] = {a0.x + r0.x, a0.y + r0.y, a0.z + r0.z, a0.w + r0.w,
                a1.x + r1.x, a1.y + r1.y, a1.z + r1.z, a1.w + r1.w};
  float s = 0.f, ss = 0.f;
#pragma unroll
  for (int j = 0; j < 8; j++) { s += v[j]; ss += v[j] * v[j]; }
#pragma unroll
  for (int m = 1; m < 64; m <<= 1) { s += __shfl_xor(s, m); ss += __shfl_xor(ss, m); }
  float mu = s * (1.f / 512.f);
  float rstd = rsqrtf(ss * (1.f / 512.f) - mu * mu + 1e-5f);
  int c0 = lane * 8;
  float o[8];
  u32x4 pk;
#pragma unroll
  for (int j = 0; j < 8; j++) {
    int c = c0 + j;
    o[j] = ((v[j] - mu) * rstd * g[c] + bta[c]) * nonpad;
  }
  float4* xo = (float4*)(xf + (size_t)row * 512 + c0);
  xo[0] = make_float4(o[0], o[1], o[2], o[3]);
  xo[1] = make_float4(o[4], o[5], o[6], o[7]);
#pragma unroll
  for (int j = 0; j < 4; j++)
    pk[j] = (unsigned)f2bf(o[2 * j]) | ((unsigned)f2bf(o[2 * j + 1]) << 16);
  *(u32x4*)(xb + (size_t)row * 512 + c0) = pk;
}

// ---------------------------------------------------------------------------
// V transpose: qkv V-part [b*1024+t][1024 + h*64+d] -> vt[(bh*64+d)][t]
// grid (32, 2, 64)
// ---------------------------------------------------------------------------
__global__ __launch_bounds__(256) void vtrans(
    const bh16* __restrict__ qkv, bh16* __restrict__ vt) {
  int bh = blockIdx.z, b = bh >> 3, h = bh & 7;
  __shared__ bh16 t[32][33];
  int t0 = blockIdx.x * 32, d0 = blockIdx.y * 32;
  int tx = threadIdx.x & 31, ty = threadIdx.x >> 5;
  const bh16* src = qkv + (size_t)(b * 1024) * 1536 + 1024 + h * 64;
#pragma unroll
  for (int i = 0; i < 4; i++)
    t[ty + 8 * i][tx] = src[(size_t)(t0 + ty + 8 * i) * 1536 + d0 + tx];
  __syncthreads();
  bh16* dst = vt + ((size_t)bh * 64 + d0) * 1024 + t0;
#pragma unroll
  for (int i = 0; i < 4; i++)
    dst[(size_t)(ty + 8 * i) * 1024 + tx] = t[tx][ty + 8 * i];
}

// ---------------------------------------------------------------------------
// Fused flash attention. grid (16 qtiles, 64 bh), 256 thr = 4 INDEPENDENT
// waves x 16 q-rows each. No barriers (P buffer is per-wave). KVBLK=64.
// Swapped QK^T: st = mfma(K, Q^T) -> lane holds S[q=lane&15][key=grp*4+r].
// K register-prefetched (double-buffer A/B via unrolled parity, rule#20-safe);
// V loads issued at iteration top so QK+softmax hides their latency.
// ---------------------------------------------------------------------------
__global__ __launch_bounds__(256) void attn_k(
    const bh16* __restrict__ qkv, const bh16* __restrict__ vt,
    const int* __restrict__ lens, bh16* __restrict__ o) {
  constexpr int LDP = 72;  // 64 P entries + pad (144B stride -> 2-way max)
  __shared__ __align__(16) bh16 P[4][16 * LDP];
  int qt = blockIdx.x, bh = blockIdx.y;
  int b = bh >> 3, h = bh & 7;
  int wave = threadIdx.x >> 6, lane = threadIdx.x & 63;
  int lq = lane & 15, grp = lane >> 4;
  int len = lens[b];

  size_t qrow = (size_t)(b * 1024 + qt * 64 + wave * 16 + lq);
  const bh16* Qp = qkv + qrow * 1536 + h * 64;
  bf16x8 qf0 = ld16(Qp + grp * 8);
  bf16x8 qf1 = ld16(Qp + 32 + grp * 8);
  const bh16* Kbase = qkv + (size_t)(b * 1024) * 1536 + 512 + h * 64;
  const bh16* Vbase = vt + (size_t)(bh * 64) * 1024;
  bh16* Pw = P[wave];

  f32x4 oacc[4] = {};
  float m = -1e30f, lsum = 0.f;
  int nkb = (len + 63) >> 6;  // keys per block never exceed 1023 (len<=1024)

  auto loadK = [&](int kb, bf16x8 (&kf)[4][2]) {
#pragma unroll
    for (int sv = 0; sv < 4; ++sv) {
      const bh16* Kp = Kbase + (size_t)(kb * 64 + sv * 16 + lq) * 1536;
      kf[sv][0] = ld16(Kp + grp * 8);
      kf[sv][1] = ld16(Kp + 32 + grp * 8);
    }
  };

  auto body = [&](int kb, bf16x8 (&kf)[4][2], bf16x8 (&kn)[4][2]) {
    int k64 = kb * 64;
    // V loads for current block (latency hidden by QK + softmax)
    bf16x8 vf[2][4];
#pragma unroll
    for (int kk = 0; kk < 2; ++kk)
#pragma unroll
      for (int dt = 0; dt < 4; ++dt)
        vf[kk][dt] =
            ld16(Vbase + (size_t)(dt * 16 + lq) * 1024 + k64 + kk * 32 + grp * 8);
    // prefetch next K block (clamped; hidden under softmax + PV)
    int kbn = (kb + 1 < nkb) ? kb + 1 : kb;
    loadK(kbn, kn);
    // QK^T
    f32x4 st[4];
    __builtin_amdgcn_s_setprio(1);
#pragma unroll
    for (int sv = 0; sv < 4; ++sv) {
      f32x4 z = {};
      z = mfma16(kf[sv][0], qf0, z);
      z = mfma16(kf[sv][1], qf1, z);
      st[sv] = z;
    }
    __builtin_amdgcn_s_setprio(0);
    // scale + mask + row-max
    float tmax = -1e30f;
#pragma unroll
    for (int sv = 0; sv < 4; ++sv)
#pragma unroll
      for (int r = 0; r < 4; ++r) {
        int key = k64 + sv * 16 + grp * 4 + r;
        float v = st[sv][r] * 0.125f;
        v = (key < len) ? v : -1e30f;
        st[sv][r] = v;
        tmax = fmaxf(tmax, v);
      }
    tmax = fmaxf(tmax, __shfl_xor(tmax, 16));
    tmax = fmaxf(tmax, __shfl_xor(tmax, 32));
    // defer-max (T13, THR=8): skip rescale when max growth is small
    float newm = fmaxf(m, tmax);
    if (!__all(newm - m <= 8.f)) {
      float sc = __expf(m - newm);
      m = newm;
      lsum *= sc;
#pragma unroll
      for (int r = 0; r < 4; ++r) {
        float scr = __shfl(sc, grp * 4 + r);
#pragma unroll
        for (int dt = 0; dt < 4; ++dt) oacc[dt][r] *= scr;
      }
    }
    // P = exp(S - m), row-sum, store to per-wave LDS (row=q, 64 entries)
    float rs = 0.f;
#pragma unroll
    for (int sv = 0; sv < 4; ++sv) {
      float p0 = __expf(st[sv][0] - m), p1 = __expf(st[sv][1] - m);
      float p2 = __expf(st[sv][2] - m), p3 = __expf(st[sv][3] - m);
      rs += (p0 + p1) + (p2 + p3);
      u32x2 pk;
      pk[0] = (unsigned)f2bf(p0) | ((unsigned)f2bf(p1) << 16);
      pk[1] = (unsigned)f2bf(p2) | ((unsigned)f2bf(p3) << 16);
      *(u32x2*)&Pw[lq * LDP + sv * 16 + grp * 4] = pk;
    }
    rs += __shfl_xor(rs, 16);
    rs += __shfl_xor(rs, 32);
    lsum += rs;
    // PV (in-wave LDS ordering: compiler-inserted lgkmcnt, no barrier)
    __builtin_amdgcn_s_setprio(1);
#pragma unroll
    for (int kk = 0; kk < 2; ++kk) {
      bf16x8 pa = ld16(Pw + lq * LDP + kk * 32 + grp * 8);
#pragma unroll
      for (int dt = 0; dt < 4; ++dt)
        oacc[dt] = mfma16(pa, vf[kk][dt], oacc[dt]);
    }
    __builtin_amdgcn_s_setprio(0);
  };

  bf16x8 kA[4][2], kB[4][2];
  loadK(0, kA);
  for (int kb = 0; kb < nkb; kb += 2) {
    body(kb, kA, kB);
    if (kb + 1 < nkb) body(kb + 1, kB, kA);
  }

  // normalize + store
#pragma unroll
  for (int r = 0; r < 4; ++r) {
    float li = __shfl(lsum, grp * 4 + r);
    float inv = 1.f / li;
    int row = qt * 64 + wave * 16 + grp * 4 + r;
    bh16* orow = o + (size_t)(b * 1024 + row) * 512 + h * 64;
#pragma unroll
    for (int dt = 0; dt < 4; ++dt) orow[dt * 16 + lq] = f2bf(oacc[dt][r] * inv);
  }
}

// ---------------------------------------------------------------------------
// host
// ---------------------------------------------------------------------------
extern "C" void kernel_launch(void* const* d_in, const int* in_sizes, int n_in,
                              void* d_out, int out_size, void* d_ws, size_t ws_size,
                              hipStream_t stream) {
  const float* padded = (const float*)d_in[0];
  const int* lens = (const int*)d_in[1];
  const float* w_in = (const float*)d_in[2];
  const float* b_in = (const float*)d_in[3];
  const float* ln_in_g = (const float*)d_in[4];
  const float* ln_in_b = (const float*)d_in[5];
  const float* pe = (const float*)d_in[6];
  const float* wq = (const float*)d_in[7];
  const float* bq = (const float*)d_in[8];
  const float* wk = (const float*)d_in[9];
  const float* bk = (const float*)d_in[10];
  const float* wv = (const float*)d_in[11];
  const float* bv = (const float*)d_in[12];
  const float* wfc = (const float*)d_in[13];
  const float* bfc = (const float*)d_in[14];
  const float* ln1_g = (const float*)d_in[15];
  const float* ln1_b = (const float*)d_in[16];
  const float* w1 = (const float*)d_in[17];
  const float* b1 = (const float*)d_in[18];
  const float* w2 = (const float*)d_in[19];
  const float* b2 = (const float*)d_in[20];
  const float* ln2_g = (const float*)d_in[21];
  const float* ln2_b = (const float*)d_in[22];

  char* ws = (char*)d_ws;
  size_t off = 0;
  auto alloc = [&](size_t bytes) -> char* {
    char* p = ws + off;
    off += (bytes + 255) & ~(size_t)255;
    return p;
  };
  bh16* WinT  = (bh16*)alloc((size_t)512 * 320 * 2);
  bh16* WqkvT = (bh16*)alloc((size_t)6 * 1536 * 512 * 2);
  bh16* WfcT  = (bh16*)alloc((size_t)6 * 512 * 512 * 2);
  bh16* W1T   = (bh16*)alloc((size_t)6 * 2048 * 512 * 2);
  bh16* W2T   = (bh16*)alloc((size_t)6 * 512 * 2048 * 2);
  float* bqkv = (float*)alloc((size_t)6 * 1536 * 4);
  bh16* xb    = (bh16*)alloc((size_t)8192 * 512 * 2);
  float* xf   = (float*)alloc((size_t)8192 * 512 * 4);
  bh16* qkvb  = (bh16*)alloc((size_t)8192 * 1536 * 2);
  bh16* vt    = (bh16*)alloc((size_t)64 * 64 * 1024 * 2);
  bh16* ob    = (bh16*)alloc((size_t)8192 * 512 * 2);
  float* tmp32 = (float*)alloc((size_t)8192 * 512 * 4);
  bh16* hbuf  = (bh16*)alloc((size_t)8192 * 2048 * 2);
  bh16* padb  = hbuf;  // alias: hbuf is free until w1 GEMM
  if (off > ws_size) return;  // loud failure (output stays poisoned)

  // weights -> bf16 transposed
  tcvt<<<dim3(16, 10, 1), 256, 0, stream>>>(w_in, WinT, 320, 512, 0, 0, 0);
  tcvt<<<dim3(16, 16, 6), 256, 0, stream>>>(wq, WqkvT, 512, 512, 512 * 512, 1536 * 512, 0);
  tcvt<<<dim3(16, 16, 6), 256, 0, stream>>>(wk, WqkvT, 512, 512, 512 * 512, 1536 * 512, 512);
  tcvt<<<dim3(16, 16, 6), 256, 0, stream>>>(wv, WqkvT, 512, 512, 512 * 512, 1536 * 512, 1024);
  tcvt<<<dim3(16, 16, 6), 256, 0, stream>>>(wfc, WfcT, 512, 512, 512 * 512, 512 * 512, 0);
  tcvt<<<dim3(64, 16, 6), 256, 0, stream>>>(w1, W1T, 512, 2048, (long long)512 * 2048, (long long)2048 * 512, 0);
  tcvt<<<dim3(16, 64, 6), 256, 0, stream>>>(w2, W2T, 2048, 512, (long long)2048 * 512, (long long)512 * 2048, 0);
  bcat<<<6, 256, 0, stream>>>(bq, bk, bv, bqkv);
  cvt_in<<<2560, 256, 0, stream>>>(padded, padb, 655360);

  // input projection + LN + PE
  gemm_bt<128, 64, 0, 1><<<dim3(8, 64), 256, 0, stream>>>(
      padb, WinT, b_in, tmp32, 8192, 512, 320);
  ln_pe_k<<<2048, 256, 0, stream>>>(tmp32, ln_in_g, ln_in_b, pe, xf, xb);

  for (int l = 0; l < 6; ++l) {
    gemm_bt<128, 128, 0, 0><<<dim3(12, 64), 256, 0, stream>>>(
        xb, WqkvT + (size_t)l * 1536 * 512, bqkv + l * 1536, qkvb, 8192, 1536, 512);
    vtrans<<<dim3(32, 2, 64), 256, 0, stream>>>(qkvb, vt);
    attn_k<<<dim3(16, 64), 256, 0, stream>>>(qkvb, vt, lens, ob);
    gemm_bt<128, 64, 0, 1><<<dim3(8, 64), 256, 0, stream>>>(
        ob, WfcT + (size_t)l * 512 * 512, bfc + l * 512, tmp32, 8192, 512, 512);
    ln_res_k<<<2048, 256, 0, stream>>>(tmp32, xf, ln1_g + l * 512, ln1_b + l * 512,
                                       lens, xf, xb);
    gemm_bt<128, 128, 1, 0><<<dim3(16, 64), 256, 0, stream>>>(
        xb, W1T + (size_t)l * 2048 * 512, b1 + l * 2048, hbuf, 8192, 2048, 512);
    gemm_bt<128, 64, 0, 1><<<dim3(8, 64), 256, 0, stream>>>(
        hbuf, W2T + (size_t)l * 512 * 2048, b2 + l * 512, tmp32, 8192, 512, 2048);
    float* xfo = (l == 5) ? (float*)d_out : xf;
    ln_res_k<<<2048, 256, 0, stream>>>(tmp32, xf, ln2_g + l * 512, ln2_b + l * 512,
                                       lens, xfo, xb);
  }
}

// Round 3
// 1361.410 us; speedup vs baseline: 1.0737x; 1.0737x over previous
//
#include <hip/hip_runtime.h>
#include <hip/hip_bf16.h>

// ---------------------------------------------------------------------------
// Transformer encoder, B=8 T=1024 D_IN=320 L=6 H=8 DK=DV=64 DM=512 DI=2048.
// bf16 MFMA GEMMs (m97-style 2-phase structure), fused flash attention with
// swapped QK^T, f32 residual stream for accuracy.
// R2 post-mortem: K reg-prefetch bloated VGPR 56->92, occupancy 37->17%,
//   latency-bound attn regressed. R3: TLP-first attn — 128-thr blocks (2
//   independent waves, no barrier), KVBLK=32, no prefetch, tail-only mask.
// ---------------------------------------------------------------------------

typedef unsigned short bh16;                                  // bf16 bits
typedef __bf16 bf16x8 __attribute__((ext_vector_type(8)));
typedef float f32x4 __attribute__((ext_vector_type(4)));
typedef unsigned int u32x4 __attribute__((ext_vector_type(4)));
typedef unsigned int u32x2 __attribute__((ext_vector_type(2)));

#define DEVI static __device__ __forceinline__

DEVI bh16 f2bf(float f) {
  union { float f; unsigned u; } x; x.f = f;
  unsigned r = x.u + 0x7fffu + ((x.u >> 16) & 1u);
  return (bh16)(r >> 16);
}
DEVI float bf2f(bh16 u) {
  union { unsigned u; float f; } x; x.u = ((unsigned)u) << 16; return x.f;
}
DEVI bf16x8 ld16(const bh16* p) {
  return __builtin_bit_cast(bf16x8, *(const u32x4*)p);
}
DEVI f32x4 mfma16(bf16x8 a, bf16x8 b, f32x4 c) {
  return __builtin_amdgcn_mfma_f32_16x16x32_bf16(a, b, c, 0, 0, 0);
}
DEVI void async16(const void* g, void* l) {
  __builtin_amdgcn_global_load_lds(
      (const __attribute__((address_space(1))) void*)g,
      (__attribute__((address_space(3))) void*)l, 16, 0, 0);
}

// ---------------------------------------------------------------------------
// Weight transpose + f32->bf16 convert: in [K][N] f32 -> out [N][K] bf16.
// grid: (N/32, K/32, Layers)
// ---------------------------------------------------------------------------
__global__ __launch_bounds__(256) void tcvt(
    const float* __restrict__ in, bh16* __restrict__ out,
    int K, int N, long long inLS, long long outLS, int rowOff) {
  int l = blockIdx.z;
  in += (size_t)l * inLS;
  out += (size_t)l * outLS + (size_t)rowOff * K;
  __shared__ float t[32][33];
  int n0 = blockIdx.x * 32, k0 = blockIdx.y * 32;
  int tx = threadIdx.x & 31, ty = threadIdx.x >> 5;  // 32 x 8
#pragma unroll
  for (int i = 0; i < 4; i++)
    t[ty + 8 * i][tx] = in[(size_t)(k0 + ty + 8 * i) * N + n0 + tx];
  __syncthreads();
#pragma unroll
  for (int i = 0; i < 4; i++)
    out[(size_t)(n0 + ty + 8 * i) * K + k0 + tx] = f2bf(t[tx][ty + 8 * i]);
}

// bias concat: bq|bk|bv -> [L][1536] f32
__global__ __launch_bounds__(256) void bcat(
    const float* __restrict__ bq, const float* __restrict__ bk,
    const float* __restrict__ bv, float* __restrict__ out) {
  int l = blockIdx.x;
  for (int j = threadIdx.x; j < 1536; j += 256) {
    float v = (j < 512) ? bq[l * 512 + j]
            : (j < 1024) ? bk[l * 512 + j - 512] : bv[l * 512 + j - 1024];
    out[l * 1536 + j] = v;
  }
}

// f32 -> bf16 convert (padded_input)
__global__ __launch_bounds__(256) void cvt_in(
    const float* __restrict__ in, bh16* __restrict__ out, int n4) {
  int i = blockIdx.x * 256 + threadIdx.x;
  if (i < n4) {
    float4 v = ((const float4*)in)[i];
    u32x2 pk;
    pk[0] = (unsigned)f2bf(v.x) | ((unsigned)f2bf(v.y) << 16);
    pk[1] = (unsigned)f2bf(v.z) | ((unsigned)f2bf(v.w) << 16);
    *(u32x2*)(out + (size_t)i * 4) = pk;
  }
}

// ---------------------------------------------------------------------------
// GEMM: C[M][N] = A[M][K](bf16) * Bt[N][K](bf16)^T + bias, m97-style.
// 256 threads (4 waves, 2x2), BK=64, global_load_lds staging, 16x16x32 MFMA.
// ---------------------------------------------------------------------------
template <int BM, int BN, int RELU, int OUTF32>
__global__ __launch_bounds__(256, 2) void gemm_bt(
    const bh16* __restrict__ A, const bh16* __restrict__ Bt,
    const float* __restrict__ bias, void* __restrict__ Cout,
    int M, int N, int K) {
  constexpr int BK = 64;
  __shared__ __align__(16) bh16 As[BM * BK];
  __shared__ __align__(16) bh16 Bs[BN * BK];
  const int tid = threadIdx.x;
  const int wave = tid >> 6, lane = tid & 63;
  const int lq = lane & 15, grp = lane >> 4;
  const int m0 = blockIdx.y * BM, n0 = blockIdx.x * BN;
  constexpr int FM = BM / 32, FN = BN / 32;
  const int wr = wave >> 1, wc = wave & 1;
  f32x4 acc[FM][FN] = {};

  const int nk = K / BK;
  for (int kt = 0; kt < nk; ++kt) {
#pragma unroll
    for (int i = 0; i < BM / 32; ++i) {
      int off = i * 4096 + wave * 1024 + lane * 16;
      int row = off >> 7, col = off & 127;
      const char* g = (const char*)A + ((size_t)(m0 + row) * K + kt * BK) * 2 + col;
      async16(g, (char*)As + off);
    }
#pragma unroll
    for (int i = 0; i < BN / 32; ++i) {
      int off = i * 4096 + wave * 1024 + lane * 16;
      int row = off >> 7, col = off & 127;
      const char* g = (const char*)Bt + ((size_t)(n0 + row) * K + kt * BK) * 2 + col;
      async16(g, (char*)Bs + off);
    }
    __syncthreads();
#pragma unroll
    for (int kk = 0; kk < 2; ++kk) {
      bf16x8 af[FM], bfr[FN];
#pragma unroll
      for (int i = 0; i < FM; ++i) {
        int row = wr * (BM / 2) + i * 16 + lq;
        af[i] = ld16(As + row * BK + kk * 32 + grp * 8);
      }
#pragma unroll
      for (int j = 0; j < FN; ++j) {
        int row = wc * (BN / 2) + j * 16 + lq;
        bfr[j] = ld16(Bs + row * BK + kk * 32 + grp * 8);
      }
#pragma unroll
      for (int i = 0; i < FM; ++i)
#pragma unroll
        for (int j = 0; j < FN; ++j)
          acc[i][j] = mfma16(af[i], bfr[j], acc[i][j]);
    }
    __syncthreads();
  }
  // epilogue: D layout col=lane&15, row=(lane>>4)*4+r  [m89-verified]
#pragma unroll
  for (int i = 0; i < FM; ++i) {
#pragma unroll
    for (int j = 0; j < FN; ++j) {
      int col = n0 + wc * (BN / 2) + j * 16 + lq;
      float bv = bias[col];
#pragma unroll
      for (int r = 0; r < 4; ++r) {
        int row = m0 + wr * (BM / 2) + i * 16 + grp * 4 + r;
        float v = acc[i][j][r] + bv;
        if (RELU) v = fmaxf(v, 0.f);
        if (OUTF32) ((float*)Cout)[(size_t)row * N + col] = v;
        else ((bh16*)Cout)[(size_t)row * N + col] = f2bf(v);
      }
    }
  }
}

// ---------------------------------------------------------------------------
// LayerNorm after input projection: xb/xf = LN(in)*g+b + pe[t]
// one wave per row (512 cols, 8/lane)
// ---------------------------------------------------------------------------
__global__ __launch_bounds__(256) void ln_pe_k(
    const float* __restrict__ in, const float* __restrict__ g,
    const float* __restrict__ bta, const float* __restrict__ pe,
    float* __restrict__ xf, bh16* __restrict__ xb) {
  int wave = threadIdx.x >> 6, lane = threadIdx.x & 63;
  int row = blockIdx.x * 4 + wave;
  int t = row & 1023;
  const float* xr = in + (size_t)row * 512 + lane * 8;
  float4 a0 = ((const float4*)xr)[0], a1 = ((const float4*)xr)[1];
  float v[8] = {a0.x, a0.y, a0.z, a0.w, a1.x, a1.y, a1.z, a1.w};
  float s = 0.f, ss = 0.f;
#pragma unroll
  for (int j = 0; j < 8; j++) { s += v[j]; ss += v[j] * v[j]; }
#pragma unroll
  for (int m = 1; m < 64; m <<= 1) { s += __shfl_xor(s, m); ss += __shfl_xor(ss, m); }
  float mu = s * (1.f / 512.f);
  float rstd = rsqrtf(ss * (1.f / 512.f) - mu * mu + 1e-5f);
  int c0 = lane * 8;
  float o[8];
  u32x4 pk;
#pragma unroll
  for (int j = 0; j < 8; j++) {
    int c = c0 + j;
    o[j] = (v[j] - mu) * rstd * g[c] + bta[c] + pe[(size_t)t * 512 + c];
  }
  float4* xo = (float4*)(xf + (size_t)row * 512 + c0);
  xo[0] = make_float4(o[0], o[1], o[2], o[3]);
  xo[1] = make_float4(o[4], o[5], o[6], o[7]);
#pragma unroll
  for (int j = 0; j < 4; j++)
    pk[j] = (unsigned)f2bf(o[2 * j]) | ((unsigned)f2bf(o[2 * j + 1]) << 16);
  *(u32x4*)(xb + (size_t)row * 512 + c0) = pk;
}

// ---------------------------------------------------------------------------
// LayerNorm with residual + pad-mask: out = LN(gout + res)*g+b * nonpad
// ---------------------------------------------------------------------------
__global__ __launch_bounds__(256) void ln_res_k(
    const float* __restrict__ gout, const float* __restrict__ res,
    const float* __restrict__ g, const float* __restrict__ bta,
    const int* __restrict__ lens,
    float* __restrict__ xf, bh16* __restrict__ xb) {
  int wave = threadIdx.x >> 6, lane = threadIdx.x & 63;
  int row = blockIdx.x * 4 + wave;
  int b = row >> 10, t = row & 1023;
  float nonpad = (t < lens[b]) ? 1.f : 0.f;
  const float* xr = gout + (size_t)row * 512 + lane * 8;
  const float* rr = res + (size_t)row * 512 + lane * 8;
  float4 a0 = ((const float4*)xr)[0], a1 = ((const float4*)xr)[1];
  float4 r0 = ((const float4*)rr)[0], r1 = ((const float4*)rr)[1];
  float v[8] = {a0.x + r0.x, a0.y + r0.y, a0.z + r0.z, a0.w + r0.w,
                a1.x + r1.x, a1.y + r1.y, a1.z + r1.z, a1.w + r1.w};
  float s = 0.f, ss = 0.f;
#pragma unroll
  for (int j = 0; j < 8; j++) { s += v[j]; ss += v[j] * v[j]; }
#pragma unroll
  for (int m = 1; m < 64; m <<= 1) { s += __shfl_xor(s, m); ss += __shfl_xor(ss, m); }
  float mu = s * (1.f / 512.f);
  float rstd = rsqrtf(ss * (1.f / 512.f) - mu * mu + 1e-5f);
  int c0 = lane * 8;
  float o[8];
  u32x4 pk;
#pragma unroll
  for (int j = 0; j < 8; j++) {
    int c = c0 + j;
    o[j] = ((v[j] - mu) * rstd * g[c] + bta[c]) * nonpad;
  }
  float4* xo = (float4*)(xf + (size_t)row * 512 + c0);
  xo[0] = make_float4(o[0], o[1], o[2], o[3]);
  xo[1] = make_float4(o[4], o[5], o[6], o[7]);
#pragma unroll
  for (int j = 0; j < 4; j++)
    pk[j] = (unsigned)f2bf(o[2 * j]) | ((unsigned)f2bf(o[2 * j + 1]) << 16);
  *(u32x4*)(xb + (size_t)row * 512 + c0) = pk;
}

// ---------------------------------------------------------------------------
// V transpose: qkv V-part [b*1024+t][1024 + h*64+d] -> vt[(bh*64+d)][t]
// grid (32, 2, 64)
// ---------------------------------------------------------------------------
__global__ __launch_bounds__(256) void vtrans(
    const bh16* __restrict__ qkv, bh16* __restrict__ vt) {
  int bh = blockIdx.z, b = bh >> 3, h = bh & 7;
  __shared__ bh16 t[32][33];
  int t0 = blockIdx.x * 32, d0 = blockIdx.y * 32;
  int tx = threadIdx.x & 31, ty = threadIdx.x >> 5;
  const bh16* src = qkv + (size_t)(b * 1024) * 1536 + 1024 + h * 64;
#pragma unroll
  for (int i = 0; i < 4; i++)
    t[ty + 8 * i][tx] = src[(size_t)(t0 + ty + 8 * i) * 1536 + d0 + tx];
  __syncthreads();
  bh16* dst = vt + ((size_t)bh * 64 + d0) * 1024 + t0;
#pragma unroll
  for (int i = 0; i < 4; i++)
    dst[(size_t)(ty + 8 * i) * 1024 + tx] = t[tx][ty + 8 * i];
}

// ---------------------------------------------------------------------------
// Fused flash attention, TLP-first. grid (32 qtiles, 64 bh), 128 thr =
// 2 INDEPENDENT waves x 16 q-rows. No barriers, no prefetch (min VGPR).
// KVBLK=32. Swapped QK^T: lane holds S[q=lane&15][key=grp*4+r].
// V loads issued before QK so their latency hides under MFMA+softmax.
// Tail-only key masking. Per-wave P buffer in LDS (2-way max conflicts).
// ---------------------------------------------------------------------------
__global__ __launch_bounds__(128) void attn_k(
    const bh16* __restrict__ qkv, const bh16* __restrict__ vt,
    const int* __restrict__ lens, bh16* __restrict__ o) {
  constexpr int LDP = 40;  // 32 P entries + pad; 80B row stride (16B-aligned)
  __shared__ __align__(16) bh16 P[2][16 * LDP];
  int qt = blockIdx.x, bh = blockIdx.y;
  int b = bh >> 3, h = bh & 7;
  int wave = threadIdx.x >> 6, lane = threadIdx.x & 63;
  int lq = lane & 15, grp = lane >> 4;
  int len = lens[b];

  size_t qrow = (size_t)(b * 1024 + qt * 32 + wave * 16 + lq);
  const bh16* Qp = qkv + qrow * 1536 + h * 64;
  bf16x8 qf0 = ld16(Qp + grp * 8);
  bf16x8 qf1 = ld16(Qp + 32 + grp * 8);
  const bh16* Kbase = qkv + (size_t)(b * 1024) * 1536 + 512 + h * 64;
  const bh16* Vbase = vt + (size_t)(bh * 64) * 1024;
  bh16* Pw = P[wave];

  f32x4 oacc[4] = {};
  float m = -1e30f, lsum = 0.f;
  int nkb = (len + 31) >> 5;

  for (int kb = 0; kb < nkb; ++kb) {
    int k32 = kb * 32;
    // K loads (used by QK below)
    bf16x8 kf[2][2];
#pragma unroll
    for (int sv = 0; sv < 2; ++sv) {
      const bh16* Kp = Kbase + (size_t)(k32 + sv * 16 + lq) * 1536;
      kf[sv][0] = ld16(Kp + grp * 8);
      kf[sv][1] = ld16(Kp + 32 + grp * 8);
    }
    // V loads issued now; stay in flight through QK + softmax (vmcnt counted)
    bf16x8 vf[4];
#pragma unroll
    for (int dt = 0; dt < 4; ++dt)
      vf[dt] = ld16(Vbase + (size_t)(dt * 16 + lq) * 1024 + k32 + grp * 8);
    // QK^T
    f32x4 st[2];
    __builtin_amdgcn_s_setprio(1);
#pragma unroll
    for (int sv = 0; sv < 2; ++sv) {
      f32x4 z = {};
      z = mfma16(kf[sv][0], qf0, z);
      z = mfma16(kf[sv][1], qf1, z);
      st[sv] = z;
    }
    __builtin_amdgcn_s_setprio(0);
    // scale + (tail-only) mask + row-max
    float tmax = -1e30f;
    if (k32 + 32 > len) {
#pragma unroll
      for (int sv = 0; sv < 2; ++sv)
#pragma unroll
        for (int r = 0; r < 4; ++r) {
          int key = k32 + sv * 16 + grp * 4 + r;
          float v = st[sv][r] * 0.125f;
          v = (key < len) ? v : -1e30f;
          st[sv][r] = v;
          tmax = fmaxf(tmax, v);
        }
    } else {
#pragma unroll
      for (int sv = 0; sv < 2; ++sv)
#pragma unroll
        for (int r = 0; r < 4; ++r) {
          float v = st[sv][r] * 0.125f;
          st[sv][r] = v;
          tmax = fmaxf(tmax, v);
        }
    }
    tmax = fmaxf(tmax, __shfl_xor(tmax, 16));
    tmax = fmaxf(tmax, __shfl_xor(tmax, 32));
    // defer-max (T13, THR=8)
    float newm = fmaxf(m, tmax);
    if (!__all(newm - m <= 8.f)) {
      float sc = __expf(m - newm);
      m = newm;
      lsum *= sc;
#pragma unroll
      for (int r = 0; r < 4; ++r) {
        float scr = __shfl(sc, grp * 4 + r);
#pragma unroll
        for (int dt = 0; dt < 4; ++dt) oacc[dt][r] *= scr;
      }
    }
    // P = exp(S - m), row-sum, per-wave LDS store (row=q, 32 entries)
    float rs = 0.f;
#pragma unroll
    for (int sv = 0; sv < 2; ++sv) {
      float p0 = __expf(st[sv][0] - m), p1 = __expf(st[sv][1] - m);
      float p2 = __expf(st[sv][2] - m), p3 = __expf(st[sv][3] - m);
      rs += (p0 + p1) + (p2 + p3);
      u32x2 pk;
      pk[0] = (unsigned)f2bf(p0) | ((unsigned)f2bf(p1) << 16);
      pk[1] = (unsigned)f2bf(p2) | ((unsigned)f2bf(p3) << 16);
      *(u32x2*)&Pw[lq * LDP + sv * 16 + grp * 4] = pk;
    }
    rs += __shfl_xor(rs, 16);
    rs += __shfl_xor(rs, 32);
    lsum += rs;
    // PV (in-wave LDS ordering via compiler lgkmcnt; no barrier needed)
    bf16x8 pa = ld16(Pw + lq * LDP + grp * 8);
    __builtin_amdgcn_s_setprio(1);
#pragma unroll
    for (int dt = 0; dt < 4; ++dt)
      oacc[dt] = mfma16(pa, vf[dt], oacc[dt]);
    __builtin_amdgcn_s_setprio(0);
  }
  // normalize + store
#pragma unroll
  for (int r = 0; r < 4; ++r) {
    float li = __shfl(lsum, grp * 4 + r);
    float inv = 1.f / li;
    int row = qt * 32 + wave * 16 + grp * 4 + r;
    bh16* orow = o + (size_t)(b * 1024 + row) * 512 + h * 64;
#pragma unroll
    for (int dt = 0; dt < 4; ++dt) orow[dt * 16 + lq] = f2bf(oacc[dt][r] * inv);
  }
}

// ---------------------------------------------------------------------------
// host
// ---------------------------------------------------------------------------
extern "C" void kernel_launch(void* const* d_in, const int* in_sizes, int n_in,
                              void* d_out, int out_size, void* d_ws, size_t ws_size,
                              hipStream_t stream) {
  const float* padded = (const float*)d_in[0];
  const int* lens = (const int*)d_in[1];
  const float* w_in = (const float*)d_in[2];
  const float* b_in = (const float*)d_in[3];
  const float* ln_in_g = (const float*)d_in[4];
  const float* ln_in_b = (const float*)d_in[5];
  const float* pe = (const float*)d_in[6];
  const float* wq = (const float*)d_in[7];
  const float* bq = (const float*)d_in[8];
  const float* wk = (const float*)d_in[9];
  const float* bk = (const float*)d_in[10];
  const float* wv = (const float*)d_in[11];
  const float* bv = (const float*)d_in[12];
  const float* wfc = (const float*)d_in[13];
  const float* bfc = (const float*)d_in[14];
  const float* ln1_g = (const float*)d_in[15];
  const float* ln1_b = (const float*)d_in[16];
  const float* w1 = (const float*)d_in[17];
  const float* b1 = (const float*)d_in[18];
  const float* w2 = (const float*)d_in[19];
  const float* b2 = (const float*)d_in[20];
  const float* ln2_g = (const float*)d_in[21];
  const float* ln2_b = (const float*)d_in[22];

  char* ws = (char*)d_ws;
  size_t off = 0;
  auto alloc = [&](size_t bytes) -> char* {
    char* p = ws + off;
    off += (bytes + 255) & ~(size_t)255;
    return p;
  };
  bh16* WinT  = (bh16*)alloc((size_t)512 * 320 * 2);
  bh16* WqkvT = (bh16*)alloc((size_t)6 * 1536 * 512 * 2);
  bh16* WfcT  = (bh16*)alloc((size_t)6 * 512 * 512 * 2);
  bh16* W1T   = (bh16*)alloc((size_t)6 * 2048 * 512 * 2);
  bh16* W2T   = (bh16*)alloc((size_t)6 * 512 * 2048 * 2);
  float* bqkv = (float*)alloc((size_t)6 * 1536 * 4);
  bh16* xb    = (bh16*)alloc((size_t)8192 * 512 * 2);
  float* xf   = (float*)alloc((size_t)8192 * 512 * 4);
  bh16* qkvb  = (bh16*)alloc((size_t)8192 * 1536 * 2);
  bh16* vt    = (bh16*)alloc((size_t)64 * 64 * 1024 * 2);
  bh16* ob    = (bh16*)alloc((size_t)8192 * 512 * 2);
  float* tmp32 = (float*)alloc((size_t)8192 * 512 * 4);
  bh16* hbuf  = (bh16*)alloc((size_t)8192 * 2048 * 2);
  bh16* padb  = hbuf;  // alias: hbuf is free until w1 GEMM
  if (off > ws_size) return;  // loud failure (output stays poisoned)

  // weights -> bf16 transposed
  tcvt<<<dim3(16, 10, 1), 256, 0, stream>>>(w_in, WinT, 320, 512, 0, 0, 0);
  tcvt<<<dim3(16, 16, 6), 256, 0, stream>>>(wq, WqkvT, 512, 512, 512 * 512, 1536 * 512, 0);
  tcvt<<<dim3(16, 16, 6), 256, 0, stream>>>(wk, WqkvT, 512, 512, 512 * 512, 1536 * 512, 512);
  tcvt<<<dim3(16, 16, 6), 256, 0, stream>>>(wv, WqkvT, 512, 512, 512 * 512, 1536 * 512, 1024);
  tcvt<<<dim3(16, 16, 6), 256, 0, stream>>>(wfc, WfcT, 512, 512, 512 * 512, 512 * 512, 0);
  tcvt<<<dim3(64, 16, 6), 256, 0, stream>>>(w1, W1T, 512, 2048, (long long)512 * 2048, (long long)2048 * 512, 0);
  tcvt<<<dim3(16, 64, 6), 256, 0, stream>>>(w2, W2T, 2048, 512, (long long)2048 * 512, (long long)512 * 2048, 0);
  bcat<<<6, 256, 0, stream>>>(bq, bk, bv, bqkv);
  cvt_in<<<2560, 256, 0, stream>>>(padded, padb, 655360);

  // input projection + LN + PE
  gemm_bt<128, 64, 0, 1><<<dim3(8, 64), 256, 0, stream>>>(
      padb, WinT, b_in, tmp32, 8192, 512, 320);
  ln_pe_k<<<2048, 256, 0, stream>>>(tmp32, ln_in_g, ln_in_b, pe, xf, xb);

  for (int l = 0; l < 6; ++l) {
    gemm_bt<128, 128, 0, 0><<<dim3(12, 64), 256, 0, stream>>>(
        xb, WqkvT + (size_t)l * 1536 * 512, bqkv + l * 1536, qkvb, 8192, 1536, 512);
    vtrans<<<dim3(32, 2, 64), 256, 0, stream>>>(qkvb, vt);
    attn_k<<<dim3(32, 64), 128, 0, stream>>>(qkvb, vt, lens, ob);
    gemm_bt<128, 64, 0, 1><<<dim3(8, 64), 256, 0, stream>>>(
        ob, WfcT + (size_t)l * 512 * 512, bfc + l * 512, tmp32, 8192, 512, 512);
    ln_res_k<<<2048, 256, 0, stream>>>(tmp32, xf, ln1_g + l * 512, ln1_b + l * 512,
                                       lens, xf, xb);
    gemm_bt<128, 128, 1, 0><<<dim3(16, 64), 256, 0, stream>>>(
        xb, W1T + (size_t)l * 2048 * 512, b1 + l * 2048, hbuf, 8192, 2048, 512);
    gemm_bt<128, 64, 0, 1><<<dim3(8, 64), 256, 0, stream>>>(
        hbuf, W2T + (size_t)l * 512 * 2048, b2 + l * 512, tmp32, 8192, 512, 2048);
    float* xfo = (l == 5) ? (float*)d_out : xf;
    ln_res_k<<<2048, 256, 0, stream>>>(tmp32, xf, ln2_g + l * 512, ln2_b + l * 512,
                                       lens, xfo, xb);
  }
}